// Round 5
// baseline (253.153 us; speedup 1.0000x reference)
//
#include <hip/hip_runtime.h>
#include <stdint.h>

#define XH   256      // x_size == h_size
#define NCLS 104

typedef _Float16 half2v __attribute__((ext_vector_type(2)));
typedef _Float16 half4v __attribute__((ext_vector_type(4)));
typedef _Float16 half8v __attribute__((ext_vector_type(8)));
typedef __attribute__((ext_vector_type(4))) float floatx4;

__device__ __forceinline__ void gll16(const void* g, void* l) {
    __builtin_amdgcn_global_load_lds(
        (const __attribute__((address_space(1))) unsigned*)g,
        (__attribute__((address_space(3))) unsigned*)l, 16, 0, 0);
}

__device__ __forceinline__ float fdot2f(half2v a, half2v b, float c) {
#if __has_builtin(__builtin_amdgcn_fdot2)
    return __builtin_amdgcn_fdot2(a, b, c, false);
#else
    return c + (float)a[0] * (float)b[0] + (float)a[1] * (float)b[1];
#endif
}

// ---------------------------------------------------------------------------
// Btw[n][k] fp16: n<512 -> W_{n&1}[k][n>>1] (LR-interleaved), n>=512 -> Wt[k][n-512]
// ---------------------------------------------------------------------------
__global__ __launch_bounds__(256)
void k_prep(const float* __restrict__ Wl, const float* __restrict__ Wr,
            const float* __restrict__ Wt, _Float16* __restrict__ Btw) {
    int idx = blockIdx.x * 256 + threadIdx.x;
    if (idx >= 3 * XH * XH) return;
    int n = idx >> 8, k = idx & 255;
    int m, c;
    if (n < 512) { m = n & 1; c = n >> 1; }
    else         { m = 2;     c = n - 512; }
    const float* W = (m == 0) ? Wl : (m == 1) ? Wr : Wt;
    Btw[idx] = (_Float16)W[k * XH + c];
}

// ---------------------------------------------------------------------------
// One dispatch, two block roles:
//  [0, Mb*6):      GEMM [Ylr | Yt] = f16(emb) @ Btw^T; A staged from fp32 emb
//                  with in-register convert; n-group-0 blocks also write embf.
//  [Mb*6, +Eb):    edge prep: epk[e] = {ts*512, pack_half2(1-a, a)}; row_start.
// ---------------------------------------------------------------------------
__global__ __launch_bounds__(256)
void k_gemm(const float* __restrict__ emb, const _Float16* __restrict__ Btw,
            const float* __restrict__ b_conv,
            const int* __restrict__ edge_src, const int* __restrict__ edge_dst,
            const float* __restrict__ alpha, const int* __restrict__ node_type,
            _Float16* __restrict__ Ylr, _Float16* __restrict__ Yt,
            _Float16* __restrict__ embf, int2* __restrict__ epk,
            int* __restrict__ row_start, int Mb, int E) {
    __shared__ __align__(16) _Float16 Ab[128 * 32];
    __shared__ __align__(16) _Float16 Bb[128 * 32];

    const int bx  = blockIdx.x;
    const int tid = threadIdx.x;

    if (bx >= Mb * 6) {                       // ---- edge-prep role
        int e = (bx - Mb * 6) * 256 + tid;
        if (e < E) {
            int s = edge_src[e];
            float a = alpha[e];
            half2v w = { (_Float16)(1.f - a), (_Float16)a };
            int2 p;
            p.x = node_type[s] * 512;         // Ylr element offset
            p.y = __builtin_bit_cast(int, w);
            epk[e] = p;
            int d = edge_dst[e];
            if (e == 0 || edge_dst[e - 1] != d) row_start[d] = e;
        }
        return;
    }

    // ---- GEMM role
    const int m0   = (bx / 6) * 128;
    const int ng   = bx % 6;
    const int n0   = ng * 128;
    const int lane = tid & 63;
    const int wv   = tid >> 6;       // 0..3
    const int mw   = wv >> 1;
    const int nw   = wv & 1;
    const int quad = lane >> 4;
    const int l15  = lane & 15;

    floatx4 acc[4][4];
    #pragma unroll
    for (int i = 0; i < 4; i++)
        #pragma unroll
        for (int j = 0; j < 4; j++) acc[i][j] = floatx4{0.f, 0.f, 0.f, 0.f};

    const int ar = tid >> 1;             // A row 0..127
    const int ah = (tid & 1) * 16;       // col half (16 elems)
    const int lq = lane >> 2;            // gll16 row-within-group
    const int lb = (lane & 3) * 16;      // gll16 byte col

    for (int kc = 0; kc < 8; kc++) {
        // B: async 16B staging (8 issues of 1 KB cover 128 rows x 64 B)
        #pragma unroll
        for (int i = 0; i < 2; i++) {
            int issue = wv * 2 + i;
            int row   = issue * 16 + lq;
            gll16((const char*)Btw + (size_t)(n0 + row) * 512 + kc * 64 + lb,
                  (char*)Bb + issue * 1024);
        }
        // A: fp32 load + convert + LDS store (and embf spill from ng==0)
        {
            const float* ga = &emb[(size_t)(m0 + ar) * XH + kc * 32 + ah];
            floatx4 f0 = *(const floatx4*)ga;
            floatx4 f1 = *(const floatx4*)(ga + 4);
            floatx4 f2 = *(const floatx4*)(ga + 8);
            floatx4 f3 = *(const floatx4*)(ga + 12);
            half8v h0, h1;
            #pragma unroll
            for (int i = 0; i < 4; i++) {
                h0[i]     = (_Float16)f0[i];
                h0[4 + i] = (_Float16)f1[i];
                h1[i]     = (_Float16)f2[i];
                h1[4 + i] = (_Float16)f3[i];
            }
            *(half8v*)&Ab[ar * 32 + ah]     = h0;
            *(half8v*)&Ab[ar * 32 + ah + 8] = h1;
            if (ng == 0) {
                _Float16* ep = &embf[(size_t)(m0 + ar) * XH + kc * 32 + ah];
                *(half8v*)ep       = h0;
                *(half8v*)(ep + 8) = h1;
            }
        }
        __syncthreads();
        half8v a[4];
        #pragma unroll
        for (int mt = 0; mt < 4; mt++)
            a[mt] = *(const half8v*)&Ab[(mw * 64 + mt * 16 + l15) * 32 + quad * 8];
        #pragma unroll
        for (int nt = 0; nt < 4; nt++) {
            half8v b = *(const half8v*)&Bb[(nw * 64 + nt * 16 + l15) * 32 + quad * 8];
            #pragma unroll
            for (int mt = 0; mt < 4; mt++)
                acc[mt][nt] = __builtin_amdgcn_mfma_f32_16x16x32_f16(a[mt], b, acc[mt][nt], 0, 0, 0);
        }
        __syncthreads();
    }

    const bool isT = (n0 >= 512);
    #pragma unroll
    for (int nt = 0; nt < 4; nt++) {
        int col = n0 + nw * 64 + nt * 16 + l15;
        float bias = isT ? b_conv[col - 512] : 0.f;
        #pragma unroll
        for (int mt = 0; mt < 4; mt++) {
            #pragma unroll
            for (int r = 0; r < 4; r++) {
                int row = m0 + mw * 64 + mt * 16 + quad * 4 + r;
                _Float16 val = (_Float16)(acc[mt][nt][r] + bias);
                if (isT) Yt[(size_t)row * XH + (col - 512)] = val;
                else     Ylr[(size_t)row * 512 + col] = val;
            }
        }
    }
}

// ---------------------------------------------------------------------------
// One 1024-thread block per graph; 16 wave-slots, slot s owns nodes s, s+16...
// Per edge: one 16B load of interleaved (l,r) f16 pairs + 4x v_dot2_f32_f16
// with pre-packed (1-a, a). Fused through the classifier.
// ---------------------------------------------------------------------------
__global__ __launch_bounds__(1024, 8)
void k_graph(const int* __restrict__ node_type, const int* __restrict__ child_count,
             const _Float16* __restrict__ embf,
             const _Float16* __restrict__ Ylr, const _Float16* __restrict__ Yt,
             const int2* __restrict__ epk, const int* __restrict__ row_start,
             const float* __restrict__ gate_w, const float* __restrict__ gate_b,
             const float* __restrict__ cls_w, const float* __restrict__ cls_b,
             float* __restrict__ out, int PER) {
    const int g    = blockIdx.x;
    const int tid  = threadIdx.x;
    const int lane = tid & 63;
    const int wv   = tid >> 6;          // 0..15
    const int base = g * PER;

    __shared__ float pw[16 * XH];
    __shared__ float ds[16];
    __shared__ float pooled[XH];

    float gw4[4];
    #pragma unroll
    for (int i = 0; i < 4; i++) gw4[i] = gate_w[4 * lane + i];
    const float gb = gate_b[0];

    float acc4[4] = {0.f, 0.f, 0.f, 0.f};
    float dsum = 0.f;

    int vg = base + wv;
    int c  = child_count[vg];
    int tv = node_type[vg];
    int rs = row_start[vg];

    for (int v = wv; v < PER; v += 16) {
        int cn = 0, tvn = 0, rsn = 0;
        if (v + 16 < PER) {
            cn  = child_count[vg + 16];
            tvn = node_type[vg + 16];
            rsn = row_start[vg + 16];
        }

        float h4[4];
        if (c == 0) {
            half4v hv = *(const half4v*)&embf[(size_t)tv * XH + 4 * lane];
            #pragma unroll
            for (int i = 0; i < 4; i++) h4[i] = (float)hv[i];
        } else {
            half4v yt = *(const half4v*)&Yt[(size_t)tv * XH + 4 * lane];  // bias folded
            float s4[4] = {0.f, 0.f, 0.f, 0.f};
            int e = rs, e1 = rs + c;
            for (; e + 2 <= e1; e += 2) {
                int2 p0 = epk[e], p1 = epk[e + 1];
                half8v y0 = *(const half8v*)&Ylr[(size_t)p0.x + 8 * lane];
                half8v y1 = *(const half8v*)&Ylr[(size_t)p1.x + 8 * lane];
                half2v w0 = __builtin_bit_cast(half2v, p0.y);
                half2v w1 = __builtin_bit_cast(half2v, p1.y);
                #pragma unroll
                for (int i = 0; i < 4; i++)
                    s4[i] = fdot2f(half2v{y0[2 * i], y0[2 * i + 1]}, w0, s4[i]);
                #pragma unroll
                for (int i = 0; i < 4; i++)
                    s4[i] = fdot2f(half2v{y1[2 * i], y1[2 * i + 1]}, w1, s4[i]);
            }
            if (e < e1) {
                int2 p0 = epk[e];
                half8v y0 = *(const half8v*)&Ylr[(size_t)p0.x + 8 * lane];
                half2v w0 = __builtin_bit_cast(half2v, p0.y);
                #pragma unroll
                for (int i = 0; i < 4; i++)
                    s4[i] = fdot2f(half2v{y0[2 * i], y0[2 * i + 1]}, w0, s4[i]);
            }
            #pragma unroll
            for (int i = 0; i < 4; i++)
                h4[i] = fmaxf(s4[i] + (float)yt[i], 0.f);
        }

        float sg = h4[0] * gw4[0] + h4[1] * gw4[1] + h4[2] * gw4[2] + h4[3] * gw4[3];
        #pragma unroll
        for (int o = 1; o < 64; o <<= 1) sg += __shfl_xor(sg, o);
        float ew = __expf(sg + gb);
        dsum += ew;
        #pragma unroll
        for (int i = 0; i < 4; i++) acc4[i] += ew * h4[i];

        c = cn; tv = tvn; rs = rsn; vg += 16;
    }

    #pragma unroll
    for (int i = 0; i < 4; i++) pw[wv * XH + 4 * lane + i] = acc4[i];
    if (lane == 0) ds[wv] = dsum;
    __syncthreads();

    if (tid < XH) {
        float p = 0.f, d = 0.f;
        #pragma unroll
        for (int w = 0; w < 16; w++) p += pw[w * XH + tid];
        #pragma unroll
        for (int w = 0; w < 16; w++) d += ds[w];
        pooled[tid] = p / d;
    }
    __syncthreads();

    if (tid < NCLS) {
        float o = cls_b[tid];
        #pragma unroll 8
        for (int k = 0; k < XH; k++) o += pooled[k] * cls_w[k * NCLS + tid];
        out[g * NCLS + tid] = o;
    }
}

// ---------------------------------------------------------------------------
extern "C" void kernel_launch(void* const* d_in, const int* in_sizes, int n_in,
                              void* d_out, int out_size, void* d_ws, size_t ws_size,
                              hipStream_t stream) {
    const int*   node_type   = (const int*)d_in[0];
    const int*   edge_src    = (const int*)d_in[1];
    const int*   edge_dst    = (const int*)d_in[2];
    const float* alpha       = (const float*)d_in[3];
    const int*   child_count = (const int*)d_in[4];
    // d_in[5] graph_ids unused: nodes of a graph are contiguous
    const float* emb         = (const float*)d_in[6];
    const float* Wl          = (const float*)d_in[7];
    const float* Wr          = (const float*)d_in[8];
    const float* Wt          = (const float*)d_in[9];
    const float* b_conv      = (const float*)d_in[10];
    const float* gate_w      = (const float*)d_in[11];
    const float* gate_b      = (const float*)d_in[12];
    const float* cls_w       = (const float*)d_in[13];
    const float* cls_b       = (const float*)d_in[14];

    const int N     = in_sizes[0];
    const int E     = in_sizes[1];
    const int vocab = in_sizes[6] / XH;
    const int G     = out_size / NCLS;
    const int PER   = N / G;
    const int Mb    = vocab / 128;
    const int Eb    = (E + 255) / 256;

    _Float16* Ylr  = (_Float16*)d_ws;                     // vocab*512 f16
    _Float16* Yt   = Ylr + (size_t)vocab * 512;           // vocab*256 f16
    _Float16* embf = Yt + (size_t)vocab * XH;             // vocab*256 f16
    _Float16* Btw  = embf + (size_t)vocab * XH;           // 768*256 f16
    int2*     epk  = (int2*)(Btw + 3 * XH * XH);          // E * 8B
    int*      row_start = (int*)(epk + E);                // N * 4B

    hipLaunchKernelGGL(k_prep, dim3((3 * XH * XH + 255) / 256), dim3(256), 0, stream,
                       Wl, Wr, Wt, Btw);

    hipLaunchKernelGGL(k_gemm, dim3(Mb * 6 + Eb), dim3(256), 0, stream,
                       emb, Btw, b_conv, edge_src, edge_dst, alpha, node_type,
                       Ylr, Yt, embf, epk, row_start, Mb, E);

    hipLaunchKernelGGL(k_graph, dim3(G), dim3(1024), 0, stream,
                       node_type, child_count, embf, Ylr, Yt, epk, row_start,
                       gate_w, gate_b, cls_w, cls_b, (float*)d_out, PER);
}

// Round 6
// 250.031 us; speedup vs baseline: 1.0125x; 1.0125x over previous
//
#include <hip/hip_runtime.h>
#include <stdint.h>

#define XH   256
#define NCLS 104

typedef _Float16 half2v __attribute__((ext_vector_type(2)));
typedef _Float16 half4v __attribute__((ext_vector_type(4)));
typedef _Float16 half8v __attribute__((ext_vector_type(8)));
typedef __attribute__((ext_vector_type(4))) float floatx4;

__device__ __forceinline__ void gll16(const void* g, void* l) {
    __builtin_amdgcn_global_load_lds(
        (const __attribute__((address_space(1))) unsigned*)g,
        (__attribute__((address_space(3))) unsigned*)l, 16, 0, 0);
}
__device__ __forceinline__ float fdot2f(half2v a, half2v b, float c) {
#if __has_builtin(__builtin_amdgcn_fdot2)
    return __builtin_amdgcn_fdot2(a, b, c, false);
#else
    return c + (float)a[0] * (float)b[0] + (float)a[1] * (float)b[1];
#endif
}
// LDS chunk swizzle: 2-way-max bank aliasing for b128 reads at 64B row stride
__device__ __forceinline__ int MF(int x) { return (x + (x >> 2)) & 3; }

// W16 layout (element offsets, VQ = vocab*256):
//   [0, 2VQ)   Ylr  interleaved (l,r) pairs, 512/row
//   [2VQ,3VQ)  Yl   [3VQ,4VQ) Yr   [4VQ,5VQ) Ym=(Yl+Yr)/2
//   [5VQ,6VQ)  Yt (+b_conv)         [6VQ,7VQ) embf (f16 emb)

// ---------------------------------------------------------------------------
// Btw[n][k] f16: n<512 -> W_{n&1}[k][n>>1] (LR-interleaved), n>=512 -> Wt.
// Edge classify: epk.x = special-row offset, or (ts*512)|1 for general.
// ---------------------------------------------------------------------------
__global__ __launch_bounds__(256)
void k_prep(const float* __restrict__ Wl, const float* __restrict__ Wr,
            const float* __restrict__ Wt,
            const int* __restrict__ edge_src, const int* __restrict__ edge_dst,
            const float* __restrict__ alpha, const int* __restrict__ node_type,
            _Float16* __restrict__ Btw, int2* __restrict__ epk,
            int* __restrict__ row_start, int VQ, int E) {
    int idx = blockIdx.x * 256 + threadIdx.x;
    if (idx < 3 * XH * XH) {
        int n = idx >> 8, k = idx & 255;
        int m, c;
        if (n < 512) { m = n & 1; c = n >> 1; }
        else         { m = 2;     c = n - 512; }
        const float* W = (m == 0) ? Wl : (m == 1) ? Wr : Wt;
        Btw[idx] = (_Float16)W[k * XH + c];
        return;
    }
    idx -= 3 * XH * XH;
    if (idx < E) {
        int s  = edge_src[idx];
        float a = alpha[idx];
        int ts = node_type[s];
        int x;
        if      (a == 0.0f) x = 2 * VQ + ts * 256;
        else if (a == 1.0f) x = 3 * VQ + ts * 256;
        else if (a == 0.5f) x = 4 * VQ + ts * 256;
        else                x = (ts * 512) | 1;
        half2v w = { (_Float16)(1.f - a), (_Float16)a };
        int2 p;
        p.x = x;
        p.y = __builtin_bit_cast(int, w);
        epk[idx] = p;
        int d = edge_dst[idx];
        if (idx == 0 || edge_dst[idx - 1] != d) row_start[d] = idx;
    }
}

// ---------------------------------------------------------------------------
// GEMM: 64-row strip per block, A (fp32 emb -> f16) staged to LDS ONCE (also
// emitted as embf), 6 n-groups of 128 cols, B gll16 double-buffered.
// Epilogue fans out: Ylr, Yl, Yr, Ym (shuffle pair), Yt(+bias).
// ---------------------------------------------------------------------------
__global__ __launch_bounds__(512)
void k_main(const float* __restrict__ emb, const _Float16* __restrict__ Btw,
            const float* __restrict__ b_conv, _Float16* __restrict__ W16, int VQ) {
    __shared__ __align__(16) _Float16 Ab[8][64][32];    // 32 KB, [kc][row][swizzled]
    __shared__ __align__(16) _Float16 Bb[2][128][32];   // 16 KB double buffer

    const int tid  = threadIdx.x;
    const int lane = tid & 63;
    const int wv   = tid >> 6;       // 0..7
    const int m0   = blockIdx.x * 64;
    const int mw   = wv >> 2;        // 0..1 (32-row strip)
    const int nw   = wv & 3;         // 0..3 (32-col strip)
    const int quad = lane >> 4;
    const int l15  = lane & 15;

    // ---- stage A once + emit embf
    {
        const int kh  = tid >> 8;         // 0..1
        const int u   = tid & 255;
        const int row = u >> 2, rem = u & 3;
        const int slot = rem ^ MF(row & 15);
        #pragma unroll
        for (int kc2 = 0; kc2 < 4; kc2++) {
            int kc = kc2 * 2 + kh;
            const float* ga = &emb[(size_t)(m0 + row) * XH + kc * 32 + rem * 8];
            floatx4 f0 = *(const floatx4*)ga;
            floatx4 f1 = *(const floatx4*)(ga + 4);
            half8v h;
            #pragma unroll
            for (int i = 0; i < 4; i++) { h[i] = (_Float16)f0[i]; h[4 + i] = (_Float16)f1[i]; }
            *(half8v*)&Ab[kc][row][slot * 8] = h;
            *(half8v*)&W16[(size_t)6 * VQ + (size_t)(m0 + row) * XH + kc * 32 + rem * 8] = h;
        }
    }
    // ---- prologue: stage (ng=0, kc=0) into buf 0
    const int brow = tid >> 2, pslot = tid & 3;
    const int bd = pslot ^ MF(brow & 15);
    gll16((const char*)Btw + (size_t)brow * 512 + bd * 16,
          (char*)&Bb[0][0][0] + wv * 1024);
    __syncthreads();

    int buf = 0;
    for (int ng = 0; ng < 6; ng++) {
        floatx4 acc[2][2];
        #pragma unroll
        for (int i = 0; i < 2; i++)
            #pragma unroll
            for (int j = 0; j < 2; j++) acc[i][j] = floatx4{0.f, 0.f, 0.f, 0.f};

        #pragma unroll
        for (int kc = 0; kc < 8; kc++) {
            int ni = ng * 8 + kc + 1;
            if (ni < 48) {
                int nng = ni >> 3, nkc = ni & 7;
                gll16((const char*)Btw + (size_t)(nng * 128 + brow) * 512 + nkc * 64 + bd * 16,
                      (char*)&Bb[buf ^ 1][0][0] + wv * 1024);
            }
            half8v a[2], b[2];
            #pragma unroll
            for (int mt = 0; mt < 2; mt++)
                a[mt] = *(const half8v*)&Ab[kc][mw * 32 + mt * 16 + l15][(quad ^ MF(l15)) * 8];
            #pragma unroll
            for (int nt = 0; nt < 2; nt++)
                b[nt] = *(const half8v*)&Bb[buf][nw * 32 + nt * 16 + l15][(quad ^ MF(l15)) * 8];
            #pragma unroll
            for (int nt = 0; nt < 2; nt++)
                #pragma unroll
                for (int mt = 0; mt < 2; mt++)
                    acc[mt][nt] = __builtin_amdgcn_mfma_f32_16x16x32_f16(a[mt], b[nt], acc[mt][nt], 0, 0, 0);
            __syncthreads();
            buf ^= 1;
        }

        const bool isT = (ng >= 4);
        #pragma unroll
        for (int nt = 0; nt < 2; nt++) {
            int col = ng * 128 + nw * 32 + nt * 16 + l15;
            float bias = isT ? b_conv[col - 512] : 0.f;
            #pragma unroll
            for (int mt = 0; mt < 2; mt++) {
                #pragma unroll
                for (int r = 0; r < 4; r++) {
                    int row = m0 + mw * 32 + mt * 16 + quad * 4 + r;
                    float v = acc[mt][nt][r] + bias;
                    if (isT) {
                        W16[(size_t)5 * VQ + (size_t)row * 256 + (col - 512)] = (_Float16)v;
                    } else {
                        W16[(size_t)row * 512 + col] = (_Float16)v;          // Ylr
                        float pv = __shfl_xor(v, 1);                          // partner (l<->r)
                        int cp = col >> 1;
                        if ((col & 1) == 0) {
                            W16[(size_t)2 * VQ + (size_t)row * 256 + cp] = (_Float16)v;               // Yl
                            W16[(size_t)4 * VQ + (size_t)row * 256 + cp] = (_Float16)(0.5f * (v + pv)); // Ym
                        } else {
                            W16[(size_t)3 * VQ + (size_t)row * 256 + cp] = (_Float16)v;               // Yr
                        }
                    }
                }
            }
        }
    }
}

// ---------------------------------------------------------------------------
// One 1024-thread block per graph; 16 wave-slots, slot s owns nodes s, s+16...
// Special edges (75%): one 8B/lane row. General: 16B interleaved + fdot2.
// Next node's Yt/embf row + first-edge descriptor prefetched one iter ahead.
// ---------------------------------------------------------------------------
__global__ __launch_bounds__(1024, 8)
void k_graph(const int* __restrict__ nty, const int* __restrict__ cc,
             const _Float16* __restrict__ W16,
             const int2* __restrict__ epk, const int* __restrict__ row_start,
             const float* __restrict__ gate_w, const float* __restrict__ gate_b,
             const float* __restrict__ cls_w, const float* __restrict__ cls_b,
             float* __restrict__ out, int PER, int VQ) {
    const int g    = blockIdx.x;
    const int tid  = threadIdx.x;
    const int lane = tid & 63;
    const int wv   = tid >> 6;       // 0..15
    const int base = g * PER;

    __shared__ float pw[16 * XH];
    __shared__ float ds[16];
    __shared__ float pooled[XH];

    float gw4[4];
    #pragma unroll
    for (int i = 0; i < 4; i++) gw4[i] = gate_w[4 * lane + i];
    const float gb = gate_b[0];

    float acc4[4] = {0.f, 0.f, 0.f, 0.f};
    float dsum = 0.f;

    // prime node state (yt row & first-edge descriptor prefetched)
    int vg = base + wv;
    int c  = cc[vg];
    int tv = nty[vg];
    int rs = (c > 0) ? row_start[vg] : 0;
    half4v yt = *(const half4v*)&W16[(size_t)(c == 0 ? 6 : 5) * VQ + (size_t)tv * 256 + 4 * lane];
    int2 pd0 = epk[rs];

    for (int v = wv; v < PER; v += 16) {
        const bool has = (v + 16 < PER);
        const int vns = has ? vg + 16 : vg;
        int cn  = has ? cc[vns] : 0;
        int tvn = nty[vns];
        int rsn = (has && cn > 0) ? row_start[vns] : 0;
        half4v ytn = *(const half4v*)&W16[(size_t)(cn == 0 ? 6 : 5) * VQ + (size_t)tvn * 256 + 4 * lane];
        int2 pdn = epk[rsn];

        float h4[4];
        if (c == 0) {
            #pragma unroll
            for (int i = 0; i < 4; i++) h4[i] = (float)yt[i];
        } else {
            float s4[4] = {0.f, 0.f, 0.f, 0.f};
            int2 p = pd0;
            int e = rs + 1;
            const int e1 = rs + c;
            while (true) {
                if (p.x & 1) {   // general: interleaved (l,r) pairs, fdot2
                    half8v y = *(const half8v*)&W16[(size_t)(p.x ^ 1) + 8 * lane];
                    half2v w = __builtin_bit_cast(half2v, p.y);
                    #pragma unroll
                    for (int i = 0; i < 4; i++)
                        s4[i] = fdot2f(half2v{y[2 * i], y[2 * i + 1]}, w, s4[i]);
                } else {         // special row (alpha in {0, 1, 0.5}): plain add
                    half4v y = *(const half4v*)&W16[(size_t)p.x + 4 * lane];
                    #pragma unroll
                    for (int i = 0; i < 4; i++) s4[i] += (float)y[i];
                }
                if (e >= e1) break;
                p = epk[e++];
            }
            #pragma unroll
            for (int i = 0; i < 4; i++)
                h4[i] = fmaxf(s4[i] + (float)yt[i], 0.f);   // bias folded into Yt
        }

        float sg = h4[0] * gw4[0] + h4[1] * gw4[1] + h4[2] * gw4[2] + h4[3] * gw4[3];
        #pragma unroll
        for (int o = 1; o < 64; o <<= 1) sg += __shfl_xor(sg, o);
        float ew = __expf(sg + gb);
        dsum += ew;
        #pragma unroll
        for (int i = 0; i < 4; i++) acc4[i] += ew * h4[i];

        c = cn; rs = rsn; yt = ytn; pd0 = pdn; vg = vns;
    }

    #pragma unroll
    for (int i = 0; i < 4; i++) pw[wv * XH + 4 * lane + i] = acc4[i];
    if (lane == 0) ds[wv] = dsum;
    __syncthreads();

    if (tid < XH) {
        float p = 0.f, d = 0.f;
        #pragma unroll
        for (int w = 0; w < 16; w++) p += pw[w * XH + tid];
        #pragma unroll
        for (int w = 0; w < 16; w++) d += ds[w];
        pooled[tid] = p / d;
    }
    __syncthreads();

    if (tid < NCLS) {
        float o = cls_b[tid];
        #pragma unroll 8
        for (int k = 0; k < XH; k++) o += pooled[k] * cls_w[k * NCLS + tid];
        out[g * NCLS + tid] = o;
    }
}

// ---------------------------------------------------------------------------
extern "C" void kernel_launch(void* const* d_in, const int* in_sizes, int n_in,
                              void* d_out, int out_size, void* d_ws, size_t ws_size,
                              hipStream_t stream) {
    const int*   node_type   = (const int*)d_in[0];
    const int*   edge_src    = (const int*)d_in[1];
    const int*   edge_dst    = (const int*)d_in[2];
    const float* alpha       = (const float*)d_in[3];
    const int*   child_count = (const int*)d_in[4];
    // d_in[5] graph_ids unused: nodes of a graph are contiguous
    const float* emb         = (const float*)d_in[6];
    const float* Wl          = (const float*)d_in[7];
    const float* Wr          = (const float*)d_in[8];
    const float* Wt          = (const float*)d_in[9];
    const float* b_conv      = (const float*)d_in[10];
    const float* gate_w      = (const float*)d_in[11];
    const float* gate_b      = (const float*)d_in[12];
    const float* cls_w       = (const float*)d_in[13];
    const float* cls_b       = (const float*)d_in[14];

    const int N     = in_sizes[0];
    const int E     = in_sizes[1];
    const int vocab = in_sizes[6] / XH;
    const int G     = out_size / NCLS;
    const int PER   = N / G;
    const int VQ    = vocab * 256;

    _Float16* W16 = (_Float16*)d_ws;                          // 7*VQ f16
    _Float16* Btw = W16 + (size_t)7 * VQ;                     // 768*256 f16
    int2*     epk = (int2*)(Btw + 3 * XH * XH);               // E * 8B
    int*      row_start = (int*)(epk + E);                    // N * 4B

    hipLaunchKernelGGL(k_prep, dim3((3 * XH * XH + E + 255) / 256), dim3(256), 0, stream,
                       Wl, Wr, Wt, edge_src, edge_dst, alpha, node_type,
                       Btw, epk, row_start, VQ, E);

    hipLaunchKernelGGL(k_main, dim3(vocab / 64), dim3(512), 0, stream,
                       emb, Btw, b_conv, W16, VQ);

    hipLaunchKernelGGL(k_graph, dim3(G), dim3(1024), 0, stream,
                       node_type, child_count, W16, epk, row_start,
                       gate_w, gate_b, cls_w, cls_b, (float*)d_out, PER, VQ);
}

// Round 7
// 234.806 us; speedup vs baseline: 1.0781x; 1.0648x over previous
//
#include <hip/hip_runtime.h>
#include <stdint.h>

#define XH   256
#define NCLS 104

typedef _Float16 half2v __attribute__((ext_vector_type(2)));
typedef _Float16 half4v __attribute__((ext_vector_type(4)));
typedef _Float16 half8v __attribute__((ext_vector_type(8)));
typedef __attribute__((ext_vector_type(4))) float floatx4;

__device__ __forceinline__ void gll16(const void* g, void* l) {
    __builtin_amdgcn_global_load_lds(
        (const __attribute__((address_space(1))) unsigned*)g,
        (__attribute__((address_space(3))) unsigned*)l, 16, 0, 0);
}
__device__ __forceinline__ float fdot2f(half2v a, half2v b, float c) {
#if __has_builtin(__builtin_amdgcn_fdot2)
    return __builtin_amdgcn_fdot2(a, b, c, false);
#else
    return c + (float)a[0] * (float)b[0] + (float)a[1] * (float)b[1];
#endif
}
// 16B-granule XOR swizzle within 64B groups: 2-way-max LDS bank aliasing
__device__ __forceinline__ int MF(int x) { return (x + (x >> 2)) & 3; }

// W16 sections (element offsets, VQ = vocab*256):
//   0:Yl   VQ:Yr   2VQ:Ym=(Yl+Yr)/2   3VQ:Yt(+b_conv)   4VQ:embf

// ---------------------------------------------------------------------------
// Btw[n][k] f16 (n<512: W_{n&1}[k][n>>1] LR-interleaved pairs; n>=512: Wt).
// epk[e]: x = row offset (|1 => second row at +VQ), y = packed half2 weights.
//   a==0 -> Yl row, w=(1,0); a==1 -> Yr row, w=(1,0); a==0.5 -> Ym row, w=(1,0)
//   else -> x=(ts*256)|1 (Yl row + Yr row at +VQ), w=(1-a, a)
// ---------------------------------------------------------------------------
__global__ __launch_bounds__(256)
void k_prep(const float* __restrict__ Wl, const float* __restrict__ Wr,
            const float* __restrict__ Wt,
            const int* __restrict__ edge_src, const int* __restrict__ edge_dst,
            const float* __restrict__ alpha, const int* __restrict__ node_type,
            _Float16* __restrict__ Btw, int2* __restrict__ epk,
            int* __restrict__ row_start, int VQ, int E) {
    int idx = blockIdx.x * 256 + threadIdx.x;
    if (idx < 3 * XH * XH) {
        int n = idx >> 8, k = idx & 255;
        int m, c;
        if (n < 512) { m = n & 1; c = n >> 1; }
        else         { m = 2;     c = n - 512; }
        const float* W = (m == 0) ? Wl : (m == 1) ? Wr : Wt;
        Btw[idx] = (_Float16)W[k * XH + c];
        return;
    }
    idx -= 3 * XH * XH;
    if (idx < E) {
        int s  = edge_src[idx];
        float a = alpha[idx];
        int ts = node_type[s];
        int x;
        half2v w;
        if      (a == 0.0f) { x = ts * 256;          w = half2v{1.0f16, 0.0f16}; }
        else if (a == 1.0f) { x = VQ + ts * 256;     w = half2v{1.0f16, 0.0f16}; }
        else if (a == 0.5f) { x = 2 * VQ + ts * 256; w = half2v{1.0f16, 0.0f16}; }
        else { x = (ts * 256) | 1; w = half2v{(_Float16)(1.f - a), (_Float16)a}; }
        int2 p;
        p.x = x;
        p.y = __builtin_bit_cast(int, w);
        epk[idx] = p;
        int d = edge_dst[idx];
        if (idx == 0 || edge_dst[idx - 1] != d) row_start[d] = idx;
    }
}

// ---------------------------------------------------------------------------
// Y = f16(emb) @ [Wl|Wr|Wt], operand-swapped MFMA (D: row=n, col=m) so lanes
// own consecutive n. 32 emb rows/block, single K-pass, all 768 n across 8
// waves. Epilogue: acc -> LDS (swizzled) -> coalesced 8/16B section stores.
// ---------------------------------------------------------------------------
__global__ __launch_bounds__(512, 4)
void k_main(const float* __restrict__ emb, const _Float16* __restrict__ Btw,
            const float* __restrict__ b_conv, _Float16* __restrict__ W16, int VQ) {
    __shared__ __align__(16) _Float16 Ab[32 * 256];   // 16 KB  emb tile (k-contig, swizzled)
    __shared__ __align__(16) _Float16 Bb[768 * 32];   // 48 KB  Btw k-chunk / epilogue tile

    const int tid  = threadIdx.x;
    const int lane = tid & 63;
    const int wv   = tid >> 6;        // 0..7
    const int quad = lane >> 4;
    const int l15  = lane & 15;
    const int m0   = blockIdx.x * 32;

    // ---- A-stage: 32 rows x 256 k fp32 -> f16 LDS (+ embf section)
    {
        int row = tid >> 4;           // 0..31
        int cg  = tid & 15;           // 16-elem column group
        const float* ga = &emb[(size_t)(m0 + row) * XH + cg * 16];
        floatx4 f0 = *(const floatx4*)ga;
        floatx4 f1 = *(const floatx4*)(ga + 4);
        floatx4 f2 = *(const floatx4*)(ga + 8);
        floatx4 f3 = *(const floatx4*)(ga + 12);
        half8v h0, h1;
        #pragma unroll
        for (int i = 0; i < 4; i++) {
            h0[i] = (_Float16)f0[i]; h0[4 + i] = (_Float16)f1[i];
            h1[i] = (_Float16)f2[i]; h1[4 + i] = (_Float16)f3[i];
        }
        int g0 = cg * 2, g1 = cg * 2 + 1;      // 16B granule ids (32/row)
        *(half8v*)&Ab[row * 256 + (g0 >> 2) * 32 + ((g0 & 3) ^ MF(row & 15)) * 8] = h0;
        *(half8v*)&Ab[row * 256 + (g1 >> 2) * 32 + ((g1 & 3) ^ MF(row & 15)) * 8] = h1;
        _Float16* ep = &W16[(size_t)4 * VQ + (size_t)(m0 + row) * 256 + cg * 16];
        *(half8v*)ep = h0;
        *(half8v*)(ep + 8) = h1;
    }

    auto stageB = [&](int kc) {     // 768 rows x 64 B of Btw for this k-chunk
        #pragma unroll
        for (int i = 0; i < 6; i++) {
            int grp = wv * 6 + i;                 // 48 groups of 16 rows
            int row = grp * 16 + (lane >> 2);
            int bd  = (lane & 3) ^ MF(row & 15);
            gll16((const char*)Btw + (size_t)row * 512 + kc * 64 + bd * 16,
                  (char*)Bb + grp * 1024);
        }
    };
    stageB(0);

    floatx4 acc[6][2];
    #pragma unroll
    for (int i = 0; i < 6; i++)
        #pragma unroll
        for (int j = 0; j < 2; j++) acc[i][j] = floatx4{0.f, 0.f, 0.f, 0.f};

    const int nbase = wv * 96;
    for (int kc = 0; kc < 8; kc++) {
        __syncthreads();                         // Bb[kc] arrived
        half8v af[6], bf[2];
        #pragma unroll
        for (int nt = 0; nt < 6; nt++) {
            int row = nbase + nt * 16 + l15;
            af[nt] = *(const half8v*)&Bb[row * 32 + ((quad ^ MF(l15)) * 8)];
        }
        #pragma unroll
        for (int mt = 0; mt < 2; mt++) {
            int row = mt * 16 + l15;
            bf[mt] = *(const half8v*)&Ab[row * 256 + kc * 32 + ((quad ^ MF(l15)) * 8)];
        }
        __syncthreads();                         // all reads done; Bb reusable
        if (kc < 7) stageB(kc + 1);
        #pragma unroll
        for (int nt = 0; nt < 6; nt++)
            #pragma unroll
            for (int mt = 0; mt < 2; mt++)
                acc[nt][mt] = __builtin_amdgcn_mfma_f32_16x16x32_f16(af[nt], bf[mt], acc[nt][mt], 0, 0, 0);
    }

    // ---- epilogue: acc -> Bb as [32 m][768 n] f16, 8B-granule XOR swizzle
    #pragma unroll
    for (int nt = 0; nt < 6; nt++) {
        #pragma unroll
        for (int mt = 0; mt < 2; mt++) {
            int m  = mt * 16 + l15;
            int n0 = nbase + nt * 16 + quad * 4;
            half4v hv;
            #pragma unroll
            for (int r = 0; r < 4; r++) hv[r] = (_Float16)acc[nt][mt][r];
            int gs = (n0 >> 2) ^ (m & 7);
            *(half4v*)((char*)Bb + (size_t)m * 1536 + gs * 8) = hv;
        }
    }
    __syncthreads();

    // pairs region (n<512): de-interleave -> Yl / Yr / Ym rows, 8B stores
    #pragma unroll
    for (int it = 0; it < 4; it++) {
        int u = it * 512 + tid;        // 2048 units = 32 m x 64 groups-of-8-n
        int m = u >> 6, ns = u & 63;
        int q0 = ((ns * 8) >> 2) ^ (m & 7);
        int q1 = (((ns * 8) >> 2) + 1) ^ (m & 7);
        half4v v0 = *(const half4v*)((const char*)Bb + (size_t)m * 1536 + q0 * 8);
        half4v v1 = *(const half4v*)((const char*)Bb + (size_t)m * 1536 + q1 * 8);
        float l0 = (float)v0[0], r0 = (float)v0[1], l1 = (float)v0[2], r1 = (float)v0[3];
        float l2 = (float)v1[0], r2 = (float)v1[1], l3 = (float)v1[2], r3 = (float)v1[3];
        half4v yl = { (_Float16)l0, (_Float16)l1, (_Float16)l2, (_Float16)l3 };
        half4v yr = { (_Float16)r0, (_Float16)r1, (_Float16)r2, (_Float16)r3 };
        half4v ym = { (_Float16)(0.5f * (l0 + r0)), (_Float16)(0.5f * (l1 + r1)),
                      (_Float16)(0.5f * (l2 + r2)), (_Float16)(0.5f * (l3 + r3)) };
        size_t ro = (size_t)(m0 + m) * 256 + ns * 4;
        *(half4v*)&W16[ro]          = yl;
        *(half4v*)&W16[VQ + ro]     = yr;
        *(half4v*)&W16[2 * VQ + ro] = ym;
    }
    // Yt region (n>=512): add bias, 16B stores
    #pragma unroll
    for (int it = 0; it < 2; it++) {
        int u = it * 512 + tid;        // 1024 units = 32 m x 32 groups-of-8-n
        int m = u >> 5, ns = u & 31;
        int n0 = 512 + ns * 8;
        int q0 = (n0 >> 2) ^ (m & 7);
        int q1 = ((n0 >> 2) + 1) ^ (m & 7);
        half4v v0 = *(const half4v*)((const char*)Bb + (size_t)m * 1536 + q0 * 8);
        half4v v1 = *(const half4v*)((const char*)Bb + (size_t)m * 1536 + q1 * 8);
        floatx4 b0 = *(const floatx4*)&b_conv[ns * 8];
        floatx4 b1 = *(const floatx4*)&b_conv[ns * 8 + 4];
        half8v o;
        #pragma unroll
        for (int i = 0; i < 4; i++) {
            o[i]     = (_Float16)((float)v0[i] + b0[i]);
            o[4 + i] = (_Float16)((float)v1[i] + b1[i]);
        }
        *(half8v*)&W16[(size_t)3 * VQ + (size_t)(m0 + m) * 256 + ns * 8] = o;
    }
}

// ---------------------------------------------------------------------------
// One 1024-thread block per graph; 16 wave-slots, slot s owns nodes s, s+16...
// Branch-free edge path: 2 row loads + 4 fdot2 per edge (specials hit the
// same row twice -> L1). 2-edge unroll + descriptor/next-node prefetch.
// ---------------------------------------------------------------------------
__global__ __launch_bounds__(1024, 8)
void k_graph(const int* __restrict__ nty, const int* __restrict__ cc,
             const _Float16* __restrict__ W16,
             const int2* __restrict__ epk, const int* __restrict__ row_start,
             const float* __restrict__ gate_w, const float* __restrict__ gate_b,
             const float* __restrict__ cls_w, const float* __restrict__ cls_b,
             float* __restrict__ out, int PER, int VQ, int E) {
    const int g    = blockIdx.x;
    const int tid  = threadIdx.x;
    const int lane = tid & 63;
    const int wv   = tid >> 6;       // 0..15
    const int base = g * PER;

    __shared__ float pw[16 * XH];
    __shared__ float ds[16];
    __shared__ float pooled[XH];

    float gw4[4];
    #pragma unroll
    for (int i = 0; i < 4; i++) gw4[i] = gate_w[4 * lane + i];
    const float gb = gate_b[0];

    float acc4[4] = {0.f, 0.f, 0.f, 0.f};
    float dsum = 0.f;

    int vg = base + wv;
    int c  = cc[vg];
    int tv = nty[vg];
    int rs = (c > 0) ? row_start[vg] : 0;
    half4v yt = *(const half4v*)&W16[(size_t)(c == 0 ? 4 : 3) * VQ + (size_t)tv * 256 + 4 * lane];
    int2 pd0 = epk[rs];

    for (int v = wv; v < PER; v += 16) {
        const bool has = (v + 16 < PER);
        const int vns = has ? vg + 16 : vg;
        int cn  = has ? cc[vns] : 0;
        int tvn = nty[vns];
        int rsn = (has && cn > 0) ? row_start[vns] : 0;
        half4v ytn = *(const half4v*)&W16[(size_t)(cn == 0 ? 4 : 3) * VQ + (size_t)tvn * 256 + 4 * lane];
        int2 pdn = epk[rsn];

        float h4[4];
        if (c == 0) {
            #pragma unroll
            for (int i = 0; i < 4; i++) h4[i] = (float)yt[i];
        } else {
            float s4[4] = {0.f, 0.f, 0.f, 0.f};
            int e = rs;
            const int e1 = rs + c;
            int2 p0 = pd0;
            while (e + 2 <= e1) {
                int2 p1 = epk[e + 1];
                int2 pn = epk[min(e + 2, E - 1)];
                int off0 = p0.x & ~1, d0 = (p0.x & 1) ? VQ : 0;
                int off1 = p1.x & ~1, d1 = (p1.x & 1) ? VQ : 0;
                half4v a0 = *(const half4v*)&W16[(size_t)off0 + 4 * lane];
                half4v b0 = *(const half4v*)&W16[(size_t)(off0 + d0) + 4 * lane];
                half4v a1 = *(const half4v*)&W16[(size_t)off1 + 4 * lane];
                half4v b1 = *(const half4v*)&W16[(size_t)(off1 + d1) + 4 * lane];
                half2v w0 = __builtin_bit_cast(half2v, p0.y);
                half2v w1 = __builtin_bit_cast(half2v, p1.y);
                #pragma unroll
                for (int i = 0; i < 4; i++)
                    s4[i] = fdot2f(half2v{a0[i], b0[i]}, w0, s4[i]);
                #pragma unroll
                for (int i = 0; i < 4; i++)
                    s4[i] = fdot2f(half2v{a1[i], b1[i]}, w1, s4[i]);
                p0 = pn;
                e += 2;
            }
            if (e < e1) {
                int off0 = p0.x & ~1, d0 = (p0.x & 1) ? VQ : 0;
                half4v a0 = *(const half4v*)&W16[(size_t)off0 + 4 * lane];
                half4v b0 = *(const half4v*)&W16[(size_t)(off0 + d0) + 4 * lane];
                half2v w0 = __builtin_bit_cast(half2v, p0.y);
                #pragma unroll
                for (int i = 0; i < 4; i++)
                    s4[i] = fdot2f(half2v{a0[i], b0[i]}, w0, s4[i]);
            }
            #pragma unroll
            for (int i = 0; i < 4; i++)
                h4[i] = fmaxf(s4[i] + (float)yt[i], 0.f);   // bias folded into Yt
        }

        float sg = h4[0] * gw4[0] + h4[1] * gw4[1] + h4[2] * gw4[2] + h4[3] * gw4[3];
        #pragma unroll
        for (int o = 1; o < 64; o <<= 1) sg += __shfl_xor(sg, o);
        float ew = __expf(sg + gb);
        dsum += ew;
        #pragma unroll
        for (int i = 0; i < 4; i++) acc4[i] += ew * h4[i];

        c = cn; rs = rsn; yt = ytn; pd0 = pdn; vg = vns;
    }

    #pragma unroll
    for (int i = 0; i < 4; i++) pw[wv * XH + 4 * lane + i] = acc4[i];
    if (lane == 0) ds[wv] = dsum;
    __syncthreads();

    if (tid < XH) {
        float p = 0.f, d = 0.f;
        #pragma unroll
        for (int w = 0; w < 16; w++) p += pw[w * XH + tid];
        #pragma unroll
        for (int w = 0; w < 16; w++) d += ds[w];
        pooled[tid] = p / d;
    }
    __syncthreads();

    if (tid < NCLS) {
        float o = cls_b[tid];
        #pragma unroll 8
        for (int k = 0; k < XH; k++) o += pooled[k] * cls_w[k * NCLS + tid];
        out[g * NCLS + tid] = o;
    }
}

// ---------------------------------------------------------------------------
extern "C" void kernel_launch(void* const* d_in, const int* in_sizes, int n_in,
                              void* d_out, int out_size, void* d_ws, size_t ws_size,
                              hipStream_t stream) {
    const int*   node_type   = (const int*)d_in[0];
    const int*   edge_src    = (const int*)d_in[1];
    const int*   edge_dst    = (const int*)d_in[2];
    const float* alpha       = (const float*)d_in[3];
    const int*   child_count = (const int*)d_in[4];
    // d_in[5] graph_ids unused: nodes of a graph are contiguous
    const float* emb         = (const float*)d_in[6];
    const float* Wl          = (const float*)d_in[7];
    const float* Wr          = (const float*)d_in[8];
    const float* Wt          = (const float*)d_in[9];
    const float* b_conv      = (const float*)d_in[10];
    const float* gate_w      = (const float*)d_in[11];
    const float* gate_b      = (const float*)d_in[12];
    const float* cls_w       = (const float*)d_in[13];
    const float* cls_b       = (const float*)d_in[14];

    const int N     = in_sizes[0];
    const int E     = in_sizes[1];
    const int vocab = in_sizes[6] / XH;
    const int G     = out_size / NCLS;
    const int PER   = N / G;
    const int VQ    = vocab * 256;

    _Float16* W16 = (_Float16*)d_ws;                          // 5*VQ f16
    _Float16* Btw = W16 + (size_t)5 * VQ;                     // 768*256 f16
    int2*     epk = (int2*)(Btw + 3 * XH * XH);               // E * 8B
    int*      row_start = (int*)(epk + E);                    // N * 4B

    hipLaunchKernelGGL(k_prep, dim3((3 * XH * XH + E + 255) / 256), dim3(256), 0, stream,
                       Wl, Wr, Wt, edge_src, edge_dst, alpha, node_type,
                       Btw, epk, row_start, VQ, E);

    hipLaunchKernelGGL(k_main, dim3(vocab / 32), dim3(512), 0, stream,
                       emb, Btw, b_conv, W16, VQ);

    hipLaunchKernelGGL(k_graph, dim3(G), dim3(1024), 0, stream,
                       node_type, child_count, W16, epk, row_start,
                       gate_w, gate_b, cls_w, cls_b, (float*)d_out, PER, VQ, E);
}